// Round 15
// baseline (210.111 us; speedup 1.0000x reference)
//
#include <hip/hip_runtime.h>

typedef unsigned short u16;
typedef __attribute__((ext_vector_type(8))) short short8;    // 8 bf16 (4 VGPRs)
typedef __attribute__((ext_vector_type(4))) float f32x4;
typedef __attribute__((ext_vector_type(16))) float f32x16;
typedef __attribute__((ext_vector_type(4))) unsigned short u16x4;
typedef __attribute__((ext_vector_type(2))) unsigned int uint2v;

typedef __attribute__((address_space(1))) void as1_void;
typedef __attribute__((address_space(3))) void as3_void;

// async global->LDS, 16B per lane; LDS dest = wave-uniform base + lane*16
__device__ __forceinline__ void gld16(const u16* g, u16* l) {
  __builtin_amdgcn_global_load_lds((as1_void*)g, (as3_void*)l, 16, 0, 0);
}

__device__ __forceinline__ u16 f2bf(float f) {
  unsigned u = __float_as_uint(f);
  u += 0x7fffu + ((u >> 16) & 1u);   // RNE
  return (u16)(u >> 16);
}

__device__ __forceinline__ short8 mk8(unsigned a, unsigned b, unsigned c, unsigned d) {
  union { unsigned u[4]; short8 s; } x;
  x.u[0] = a; x.u[1] = b; x.u[2] = c; x.u[3] = d;
  return x.s;
}

// ---------------- fused prep: cvt x (x4) + W_eff (x4) + cvt wo (x4) ----------------
// blocks [0,3072): x cvt; [3072,4800): weff quads; [4800,5376): wob quads. All x4 vectorized.
__global__ void prep_all(const float* __restrict__ x, u16* __restrict__ xb,
                         const float* __restrict__ wq, const float* __restrict__ wk, const float* __restrict__ wv,
                         const float* __restrict__ dq, const float* __restrict__ uq,
                         const float* __restrict__ dk, const float* __restrict__ uk,
                         const float* __restrict__ dv, const float* __restrict__ uv,
                         const float* __restrict__ wo, u16* __restrict__ weff, u16* __restrict__ wob) {
  int bid = blockIdx.x;
  if (bid < 3072) {
    int i = bid * 256 + threadIdx.x;          // < 786432
    f32x4 f = *(const f32x4*)(x + (size_t)i * 4);
    u16x4 o;
#pragma unroll
    for (int r = 0; r < 4; ++r) o[r] = f2bf(f[r]);
    *(u16x4*)(xb + (size_t)i * 4) = o;
    return;
  }
  if (bid < 4800) {
    int idx = (bid - 3072) * 256 + threadIdx.x;   // < 442368 quads (2304 rows x 192)
    int n = idx / 192, d4 = (idx - n * 192) * 4;
    const float *w, *dn, *up; int e;
    if (n < 768)       { w = wq; dn = dq; up = uq; e = n; }
    else if (n < 1536) { w = wk; dn = dk; up = uk; e = n - 768; }
    else               { w = wv; dn = dv; up = uv; e = n - 1536; }
    f32x4 acc = *(const f32x4*)(w + (size_t)e * 768 + d4);
    f32x4 lo = {0.f, 0.f, 0.f, 0.f};
#pragma unroll
    for (int r = 0; r < 8; ++r) {
      float u = up[e * 8 + r];
      f32x4 dv4 = *(const f32x4*)(dn + r * 768 + d4);
#pragma unroll
      for (int j = 0; j < 4; ++j) lo[j] += u * dv4[j];
    }
    u16x4 o;
#pragma unroll
    for (int j = 0; j < 4; ++j) o[j] = f2bf(acc[j] + 2.0f * lo[j]);  // SCALING = 2
    *(u16x4*)(weff + (size_t)n * 768 + d4) = o;
    return;
  }
  int idx = (bid - 4800) * 256 + threadIdx.x;     // < 147456 quads (768 x 192)
  f32x4 f = *(const f32x4*)(wo + (size_t)idx * 4);
  u16x4 o;
#pragma unroll
  for (int r = 0; r < 4; ++r) o[r] = f2bf(f[r]);
  *(u16x4*)(wob + (size_t)idx * 4) = o;
}

// ---------------- NT GEMM: C[m,n] = sum_k A[m,k]*B[n,k] (+bias) ----------------
// (r12 best-measured config.)
// MT=128: 128x96 tile, grid (32,24)=768 = exactly 3 blk/CU. 2x2 waves of 64x48 (TI4,TJ3).
// MT=32: 32x128, 1x4 waves of 32x32 (grid (128,6)=768).
// BK=32, 256 thr, double-buffered staging (one barrier per K-step).
// (r11 lesson: no merge fusion here — A-panels reused by col-blocks.)
// mode 0: N=2304 -> q[h][s][64] (pre-scaled by 0.125*log2e), k[h][s][64], vt[h][64][s]
// mode 1: N=768  -> fo[s][768] fp32 (+bo)
template <int MT>
__global__ __launch_bounds__(256) void gemm_nt(
    const u16* __restrict__ A, const u16* __restrict__ B, int K, int mode,
    const float* __restrict__ bq, const float* __restrict__ bk, const float* __restrict__ bv,
    u16* __restrict__ qo, u16* __restrict__ ko, u16* __restrict__ vto,
    const float* __restrict__ bo, float* __restrict__ fo) {
  constexpr int NT = (MT == 128) ? 96 : 128;
  constexpr int TI = (MT == 128) ? 4 : 2;
  constexpr int TJ = (MT == 128) ? 3 : 2;
  __shared__ u16 As[2][MT * 32];
  __shared__ u16 Bs[2][NT * 32];
  const int tid = threadIdx.x;
  const int lane = tid & 63;
  const int wid = tid >> 6;
  const int qd = lane >> 4;
  const int m16 = lane & 15;
  const int rowbase = (MT == 128) ? (wid >> 1) * 64 : 0;
  const int colbase = (MT == 128) ? (wid & 1) * 48 : wid * 32;
  const int m0 = blockIdx.x * MT, n0 = blockIdx.y * NT;

  f32x4 acc[TI][TJ];
#pragma unroll
  for (int i = 0; i < TI; ++i)
#pragma unroll
    for (int j = 0; j < TJ; ++j)
#pragma unroll
      for (int e = 0; e < 4; ++e) acc[i][j][e] = 0.f;

  // stage one 32-wide K-slice of A and B into buffer `buf`
  auto stage = [&](int buf, int k0) {
#pragma unroll
    for (int p = tid; p < MT * 4; p += 256) {
      int row = p >> 2;
      int g = (p & 3) ^ ((row >> 1) & 3);
      gld16(A + (size_t)(m0 + row) * K + k0 + g * 8, &As[buf][(p - lane) * 8]);
    }
#pragma unroll
    for (int p = tid; p < NT * 4; p += 256) {
      int row = p >> 2;
      int g = (p & 3) ^ ((row >> 1) & 3);
      gld16(B + (size_t)(n0 + row) * K + k0 + g * 8, &Bs[buf][(p - lane) * 8]);
    }
  };

  stage(0, 0);                       // prologue
  int cur = 0;
  for (int k0 = 0; k0 < K; k0 += 32) {
    __syncthreads();                 // buf[cur] staged (issued last iter); prev reads done
    if (k0 + 32 < K) stage(cur ^ 1, k0 + 32);
    const u16* as = As[cur];
    const u16* bs = Bs[cur];
    short8 af[TI], bf[TJ];
#pragma unroll
    for (int i = 0; i < TI; ++i) {
      int ar = rowbase + i * 16 + m16;
      af[i] = *(const short8*)&as[(ar * 4 + (qd ^ ((ar >> 1) & 3))) * 8];
    }
#pragma unroll
    for (int j = 0; j < TJ; ++j) {
      int br = colbase + j * 16 + m16;
      bf[j] = *(const short8*)&bs[(br * 4 + (qd ^ ((br >> 1) & 3))) * 8];
    }
#pragma unroll
    for (int i = 0; i < TI; ++i)
#pragma unroll
      for (int j = 0; j < TJ; ++j)
        acc[i][j] = __builtin_amdgcn_mfma_f32_16x16x32_bf16(af[i], bf[j], acc[i][j], 0, 0, 0);
    cur ^= 1;
  }

  // C/D layout: col = m16, row = qd*4 + reg
#pragma unroll
  for (int i = 0; i < TI; ++i) {
    int gr = m0 + rowbase + i * 16 + qd * 4;
#pragma unroll
    for (int j = 0; j < TJ; ++j) {
      int gc = n0 + colbase + j * 16 + m16;
      if (mode == 0) {
        if (gc < 768) {
          float bias = bq[gc];
          int h = gc >> 6, d = gc & 63;
          // fold attention scale 1/8 and log2(e) into Q: exp(x/8) = exp2(x*0.18034)
#pragma unroll
          for (int r = 0; r < 4; ++r)
            qo[((size_t)h * 4096 + gr + r) * 64 + d] = f2bf((acc[i][j][r] + bias) * 0.18033688f);
        } else if (gc < 1536) {
          int c = gc - 768;
          float bias = bk[c];
          int h = c >> 6, d = c & 63;
#pragma unroll
          for (int r = 0; r < 4; ++r)
            ko[((size_t)h * 4096 + gr + r) * 64 + d] = f2bf(acc[i][j][r] + bias);
        } else {
          int c = gc - 1536;
          float bias = bv[c];
          int h = c >> 6, d = c & 63;
          u16x4 pk;
#pragma unroll
          for (int r = 0; r < 4; ++r) pk[r] = f2bf(acc[i][j][r] + bias);
          *(u16x4*)&vto[((size_t)h * 64 + d) * 4096 + gr] = pk;
        }
      } else {
        float bias = bo[gc];
#pragma unroll
        for (int r = 0; r < 4; ++r)
          fo[(size_t)(gr + r) * 768 + gc] = acc[i][j][r] + bias;
      }
    }
  }
}

// ---------------- flash attention fwd (S^T form, fixed-max base-2 softmax) ----------------
// grid (12*kspl groups=(h,z), 16 qblocks), 512 thr / 8 WAVES. Wave owns ONE 32-q-row tile.
// ROUND-15 (= r14 resubmit after opaque container failure; kernel has NO sync-structure
// change — pure reordering, bitwise-identical output; r3/r4's risk class absent):
// T15-style dual-pipe overlap — QK^T for BOTH 32-k subtiles issued first (16 MFMA
// back-to-back), then softmax(s0) -> PV(pa0) -> softmax(s1) -> PV(pa1). softmax(s0)
// VALU overlaps s1's in-flight QK MFMAs; softmax(s1) overlaps PV(pa0). +16 VGPR for the
// second live S-tile (~110 unified incl AGPRs, under the 128 cap at 4 waves/SIMD).
// 8 waves amortize each staged 16KB K/V tile over 256 q-rows; 768 blocks = 3/CU; XCD
// clustering (48%8==0 -> id%8 = grp%8) keeps K/V streams L2-resident (r5: FETCH /4.5).
// V LDS staging is the layout transform (r7: global-direct V = 2x regression, uncoalesced).
// Sync = PROVEN syncthreads double-buffer (raw-barrier pipeline killed containers r3/r4).
// O-partials stored as BF16 (r12: halves attn WRITE + merge read; error <=8e-5). l stays f32.
// 32x32x16 MFMA. Swapped QK^T: S^T = K*Q^T, lane (q32=lane&31, hf=lane>>5) holds 16 scores
// of q-row q32, k = (reg&3)+8*(reg>>2)+4*hf. Softmax in-register; P for PV built via
// v_cvt_pk_bf16_f32 + permlane32_swap pairing (w0,w2)/(w1,w3) -> A-frag layout k=(l>>5)*8+j.
// K buf 64x64 (8 chunks/row, phys = row*8 + (c ^ (row&7))); V^T buf 64d x 64k same swizzle,
// double-buffered, 32 KB LDS.
__global__ __launch_bounds__(512, 4) void attn_fwd(
    const u16* __restrict__ Q, const u16* __restrict__ Kg, const u16* __restrict__ Vt,
    u16* __restrict__ Opart, float* __restrict__ lpart, u16* __restrict__ abo, int kspl) {
  __shared__ u16 Ks[2][64 * 64];
  __shared__ u16 Vs[2][64 * 64];
  const int tid = threadIdx.x, lane = tid & 63, wid = tid >> 6;
  const int q32 = lane & 31, hf = lane >> 5;
  const int grp = blockIdx.x;
  const int h = grp / kspl;
  const int z = grp - h * kspl;
  const int qrow = blockIdx.y * 256 + wid * 32;
  const int kbase = z * (4096 / kspl);
  const int niter = (4096 / kspl) >> 6;

  const u16* kgh = Kg + (size_t)h * 4096 * 64;
  const u16* vth = Vt + (size_t)h * 64 * 4096;

  // Q fragment (B-operand of K*Q^T): qf[ds] = Q[qrow+q32][ds*16 + hf*8 ..+8)
  short8 qf[4];
  {
    const u16* qb = Q + ((size_t)h * 4096 + qrow + q32) * 64 + hf * 8;
#pragma unroll
    for (int ds = 0; ds < 4; ++ds) qf[ds] = *(const short8*)(qb + ds * 16);
  }

  float lrun = 0.f;
  f32x16 oacc[2];
#pragma unroll
  for (int d = 0; d < 2; ++d)
#pragma unroll
    for (int r = 0; r < 16; ++r) oacc[d][r] = 0.f;

  // persistent zero C-operand for the QK MFMA chain (avoids re-zeroing 16 regs per subtile)
  f32x16 zv;
#pragma unroll
  for (int r = 0; r < 16; ++r) zv[r] = 0.f;

  // prologue: stage iter 0 into buffer 0 (512 thr -> 1 K-chunk + 1 V-chunk each)
  {
    const int kt = kbase;
    int p = tid;                              // 0..511 chunks
    int row = p >> 3;
    int g = (p & 7) ^ (row & 7);
    gld16(kgh + (size_t)(kt + row) * 64 + g * 8, &Ks[0][(p - lane) * 8]);
    gld16(vth + (size_t)row * 4096 + kt + g * 8, &Vs[0][(p - lane) * 8]);
  }

  for (int it = 0; it < niter; ++it) {
    __syncthreads();   // buf[it&1] staged (issued last iter); prev reads of buf^1 done
    if (it + 1 < niter) {
      const int kt = kbase + (it + 1) * 64;
      const int b = (it + 1) & 1;
      int p = tid;
      int row = p >> 3;
      int g = (p & 7) ^ (row & 7);
      gld16(kgh + (size_t)(kt + row) * 64 + g * 8, &Ks[b][(p - lane) * 8]);
      gld16(vth + (size_t)row * 4096 + kt + g * 8, &Vs[b][(p - lane) * 8]);
    }
    const u16* ks = Ks[it & 1];
    const u16* vs = Vs[it & 1];

    // -------- Phase 1: QK^T for BOTH 32-k subtiles (MFMA pipe, issued back-to-back) ----
    f32x16 s0, s1;
    {
      short8 kf[4];
#pragma unroll
      for (int ds = 0; ds < 4; ++ds) {
        int c = ds * 2 + hf;
        int krow = q32;                       // kst = 0
        kf[ds] = *(const short8*)&ks[((krow << 3) + (c ^ (krow & 7))) * 8];
      }
      __builtin_amdgcn_s_setprio(1);
      s0 = __builtin_amdgcn_mfma_f32_32x32x16_bf16(kf[0], qf[0], zv, 0, 0, 0);
#pragma unroll
      for (int ds = 1; ds < 4; ++ds)
        s0 = __builtin_amdgcn_mfma_f32_32x32x16_bf16(kf[ds], qf[ds], s0, 0, 0, 0);
      __builtin_amdgcn_s_setprio(0);
    }
    {
      short8 kf[4];
#pragma unroll
      for (int ds = 0; ds < 4; ++ds) {
        int c = ds * 2 + hf;
        int krow = 32 + q32;                  // kst = 1
        kf[ds] = *(const short8*)&ks[((krow << 3) + (c ^ (krow & 7))) * 8];
      }
      __builtin_amdgcn_s_setprio(1);
      s1 = __builtin_amdgcn_mfma_f32_32x32x16_bf16(kf[0], qf[0], zv, 0, 0, 0);
#pragma unroll
      for (int ds = 1; ds < 4; ++ds)
        s1 = __builtin_amdgcn_mfma_f32_32x32x16_bf16(kf[ds], qf[ds], s1, 0, 0, 0);
      __builtin_amdgcn_s_setprio(0);
    }

    // -------- Phase 2/3 per subtile: softmax (VALU) then PV (MFMA) ----------------------
    // softmax(s0) overlaps s1's in-flight QK MFMAs; softmax(s1) overlaps PV(pa0)'s MFMAs.
#pragma unroll
    for (int kst = 0; kst < 2; ++kst) {       // static unroll -> s pick is compile-time
      f32x16 s = (kst == 0) ? s0 : s1;
      unsigned w[8];
      float ls0 = 0.f, ls1 = 0.f;
#pragma unroll
      for (int i = 0; i < 8; ++i) {
        float p0 = __builtin_amdgcn_exp2f(s[2 * i]);
        float p1 = __builtin_amdgcn_exp2f(s[2 * i + 1]);
        if (i & 1) ls1 += p0 + p1; else ls0 += p0 + p1;
        asm("v_cvt_pk_bf16_f32 %0, %1, %2" : "=v"(w[i]) : "v"(p0), "v"(p1));
      }
      lrun += ls0 + ls1;
      uint2v r0 = __builtin_amdgcn_permlane32_swap(w[0], w[2], false, false);
      uint2v r1 = __builtin_amdgcn_permlane32_swap(w[1], w[3], false, false);
      uint2v r2 = __builtin_amdgcn_permlane32_swap(w[4], w[6], false, false);
      uint2v r3 = __builtin_amdgcn_permlane32_swap(w[5], w[7], false, false);
      short8 pa[2];
      pa[0] = mk8(r0[0], r1[0], r0[1], r1[1]);   // k-slice kst*32 + [0,16)
      pa[1] = mk8(r2[0], r3[0], r2[1], r3[1]);   // k-slice kst*32 + [16,32)
      // O += P V for this subtile (all in registers; V from swizzled LDS)
      __builtin_amdgcn_s_setprio(1);
#pragma unroll
      for (int dt = 0; dt < 2; ++dt) {
        const int vrow = dt * 32 + q32;
#pragma unroll
        for (int ksl = 0; ksl < 2; ++ksl) {
          int c = kst * 4 + ksl * 2 + hf;
          short8 vf = *(const short8*)&vs[((vrow << 3) + (c ^ (vrow & 7))) * 8];
          oacc[dt] = __builtin_amdgcn_mfma_f32_32x32x16_bf16(pa[ksl], vf, oacc[dt], 0, 0, 0);
        }
      }
      __builtin_amdgcn_s_setprio(0);
    }
  }

  // each half holds a disjoint k-partial of the row sum; combine across halves
  lrun += __shfl_xor(lrun, 32);

  if (kspl > 1) {
    if (hf == 0)
      lpart[((size_t)z * 4096 + qrow + q32) * 12 + h] = lrun;
    u16* ob = Opart + (size_t)z * 4096 * 768;
#pragma unroll
    for (int r = 0; r < 16; ++r) {
      int qloc = (r & 3) + 8 * (r >> 2) + 4 * hf;
#pragma unroll
      for (int dt = 0; dt < 2; ++dt)
        ob[(size_t)(qrow + qloc) * 768 + h * 64 + dt * 32 + q32] = f2bf(oacc[dt][r]);
    }
  } else {
    float linv = 1.0f / lrun;
#pragma unroll
    for (int r = 0; r < 16; ++r) {
      int qloc = (r & 3) + 8 * (r >> 2) + 4 * hf;
      float li = __shfl(linv, qloc);
#pragma unroll
      for (int dt = 0; dt < 2; ++dt)
        abo[(size_t)(qrow + qloc) * 768 + h * 64 + dt * 32 + q32] =
            f2bf(oacc[dt][r] * li);
    }
  }
}

// ---------------- merge ksp k-split bf16 partials + normalize -> bf16, x4 ----------------
__global__ void merge_norm(const u16* __restrict__ Opart, const float* __restrict__ lpart,
                           u16* __restrict__ abo, int ksp) {
  int i = blockIdx.x * 256 + threadIdx.x;   // < 786432 (4096*768/4)
  int s = i / 192, cq = i - s * 192;
  int h = cq >> 4;                          // (cq*4)>>6
  f32x4 a = {0.f, 0.f, 0.f, 0.f};
  float l = 0.f;
  for (int z = 0; z < ksp; ++z) {
    u16x4 b = *(const u16x4*)(Opart + (size_t)z * 4096 * 768 + (size_t)i * 4);
#pragma unroll
    for (int r = 0; r < 4; ++r) a[r] += __uint_as_float((unsigned)b[r] << 16);
    l += lpart[((size_t)z * 4096 + s) * 12 + h];
  }
  float rl = 1.0f / l;
  u16x4 o;
#pragma unroll
  for (int r = 0; r < 4; ++r) o[r] = f2bf(a[r] * rl);
  *(u16x4*)(abo + (size_t)i * 4) = o;
}

extern "C" void kernel_launch(void* const* d_in, const int* in_sizes, int n_in,
                              void* d_out, int out_size, void* d_ws, size_t ws_size,
                              hipStream_t stream) {
  const float* x   = (const float*)d_in[0];
  const float* wq  = (const float*)d_in[1];
  const float* bq  = (const float*)d_in[2];
  const float* wk  = (const float*)d_in[3];
  const float* bk  = (const float*)d_in[4];
  const float* wv  = (const float*)d_in[5];
  const float* bv  = (const float*)d_in[6];
  const float* wo  = (const float*)d_in[7];
  const float* bo  = (const float*)d_in[8];
  const float* dq  = (const float*)d_in[9];
  const float* uq  = (const float*)d_in[10];
  const float* dk  = (const float*)d_in[11];
  const float* uk  = (const float*)d_in[12];
  const float* dv  = (const float*)d_in[13];
  const float* uv  = (const float*)d_in[14];
  float* out = (float*)d_out;

  char* ws = (char*)d_ws;
  u16* xb    = (u16*)(ws);                 // 4096*768 bf16 (6291456 B); dead after QKV gemm
  u16* ab    = (u16*)(ws);                 // aliases xb: attn output [4096][768] bf16
  u16* weff  = (u16*)(ws + 6291456);       // 2304*768
  u16* wob   = (u16*)(ws + 9830400);       // 768*768
  u16* qb    = (u16*)(ws + 11010048);      // [12][4096][64]
  u16* kb    = (u16*)(ws + 17301504);      // [12][4096][64]
  u16* vtb   = (u16*)(ws + 23592960);      // [12][64][4096]
  u16* Op    = (u16*)(ws + 29884416);      // [kspl][4096][768] bf16 (<= 25165824 B)
  float* lp  = (float*)(ws + 55050240);    // [kspl][4096][12]  f32 (<= 786432 B) -> end 55836672

  int kspl = 1;
  if (ws_size >= 55836672ull) kspl = 4;    // bf16 partials: kspl=4 fits in ~56MB
  else if (ws_size >= 42860544ull) kspl = 2;

  prep_all<<<5376, 256, 0, stream>>>(x, xb, wq, wk, wv, dq, uq, dk, uk, dv, uv, wo, weff, wob);
  gemm_nt<128><<<dim3(32, 24), 256, 0, stream>>>(xb, weff, 768, 0, bq, bk, bv, qb, kb, vtb,
                                                 nullptr, nullptr);
  attn_fwd<<<dim3(12 * kspl, 16), 512, 0, stream>>>(qb, kb, vtb, Op, lp, ab, kspl);
  if (kspl > 1) merge_norm<<<3072, 256, 0, stream>>>(Op, lp, ab, kspl);
  gemm_nt<32><<<dim3(128, 6), 256, 0, stream>>>(ab, wob, 768, 1, nullptr, nullptr, nullptr,
                                                nullptr, nullptr, nullptr, bo, out);
}

// Round 16
// 201.914 us; speedup vs baseline: 1.0406x; 1.0406x over previous
//
#include <hip/hip_runtime.h>

typedef unsigned short u16;
typedef __attribute__((ext_vector_type(8))) short short8;    // 8 bf16 (4 VGPRs)
typedef __attribute__((ext_vector_type(4))) float f32x4;
typedef __attribute__((ext_vector_type(16))) float f32x16;
typedef __attribute__((ext_vector_type(4))) unsigned short u16x4;
typedef __attribute__((ext_vector_type(8))) unsigned short u16x8;
typedef __attribute__((ext_vector_type(2))) unsigned int uint2v;

typedef __attribute__((address_space(1))) void as1_void;
typedef __attribute__((address_space(3))) void as3_void;

// async global->LDS, 16B per lane; LDS dest = wave-uniform base + lane*16
__device__ __forceinline__ void gld16(const u16* g, u16* l) {
  __builtin_amdgcn_global_load_lds((as1_void*)g, (as3_void*)l, 16, 0, 0);
}

__device__ __forceinline__ u16 f2bf(float f) {
  unsigned u = __float_as_uint(f);
  u += 0x7fffu + ((u >> 16) & 1u);   // RNE
  return (u16)(u >> 16);
}

__device__ __forceinline__ short8 mk8(unsigned a, unsigned b, unsigned c, unsigned d) {
  union { unsigned u[4]; short8 s; } x;
  x.u[0] = a; x.u[1] = b; x.u[2] = c; x.u[3] = d;
  return x.s;
}

// ---------------- fused prep: cvt x (x4) + W_eff (x4) + cvt wo (x4) ----------------
// blocks [0,3072): x cvt; [3072,4800): weff quads; [4800,5376): wob quads. All x4 vectorized.
__global__ void prep_all(const float* __restrict__ x, u16* __restrict__ xb,
                         const float* __restrict__ wq, const float* __restrict__ wk, const float* __restrict__ wv,
                         const float* __restrict__ dq, const float* __restrict__ uq,
                         const float* __restrict__ dk, const float* __restrict__ uk,
                         const float* __restrict__ dv, const float* __restrict__ uv,
                         const float* __restrict__ wo, u16* __restrict__ weff, u16* __restrict__ wob) {
  int bid = blockIdx.x;
  if (bid < 3072) {
    int i = bid * 256 + threadIdx.x;          // < 786432
    f32x4 f = *(const f32x4*)(x + (size_t)i * 4);
    u16x4 o;
#pragma unroll
    for (int r = 0; r < 4; ++r) o[r] = f2bf(f[r]);
    *(u16x4*)(xb + (size_t)i * 4) = o;
    return;
  }
  if (bid < 4800) {
    int idx = (bid - 3072) * 256 + threadIdx.x;   // < 442368 quads (2304 rows x 192)
    int n = idx / 192, d4 = (idx - n * 192) * 4;
    const float *w, *dn, *up; int e;
    if (n < 768)       { w = wq; dn = dq; up = uq; e = n; }
    else if (n < 1536) { w = wk; dn = dk; up = uk; e = n - 768; }
    else               { w = wv; dn = dv; up = uv; e = n - 1536; }
    f32x4 acc = *(const f32x4*)(w + (size_t)e * 768 + d4);
    f32x4 lo = {0.f, 0.f, 0.f, 0.f};
#pragma unroll
    for (int r = 0; r < 8; ++r) {
      float u = up[e * 8 + r];
      f32x4 dv4 = *(const f32x4*)(dn + r * 768 + d4);
#pragma unroll
      for (int j = 0; j < 4; ++j) lo[j] += u * dv4[j];
    }
    u16x4 o;
#pragma unroll
    for (int j = 0; j < 4; ++j) o[j] = f2bf(acc[j] + 2.0f * lo[j]);  // SCALING = 2
    *(u16x4*)(weff + (size_t)n * 768 + d4) = o;
    return;
  }
  int idx = (bid - 4800) * 256 + threadIdx.x;     // < 147456 quads (768 x 192)
  f32x4 f = *(const f32x4*)(wo + (size_t)idx * 4);
  u16x4 o;
#pragma unroll
  for (int r = 0; r < 4; ++r) o[r] = f2bf(f[r]);
  *(u16x4*)(wob + (size_t)idx * 4) = o;
}

// ---------------- NT GEMM: C[m,n] = sum_k A[m,k]*B[n,k] (+bias) ----------------
// (r12 best-measured config — 203.1us total. r13's 512-thr/64x96 variants neutral; r15's
//  attn reorder mildly negative. Locked.)
// MT=128: 128x96 tile, grid (32,24)=768 = exactly 3 blk/CU. 2x2 waves of 64x48 (TI4,TJ3).
// MT=32: 32x128, 1x4 waves of 32x32 (grid (128,6)=768).
// BK=32, 256 thr, double-buffered staging (one barrier per K-step).
// (r11 lesson: no merge fusion here — A-panels reused by col-blocks.)
// mode 0: N=2304 -> q[h][s][64] (pre-scaled by 0.125*log2e), k[h][s][64], vt[h][64][s]
// mode 1: N=768  -> fo[s][768] fp32 (+bo)
template <int MT>
__global__ __launch_bounds__(256) void gemm_nt(
    const u16* __restrict__ A, const u16* __restrict__ B, int K, int mode,
    const float* __restrict__ bq, const float* __restrict__ bk, const float* __restrict__ bv,
    u16* __restrict__ qo, u16* __restrict__ ko, u16* __restrict__ vto,
    const float* __restrict__ bo, float* __restrict__ fo) {
  constexpr int NT = (MT == 128) ? 96 : 128;
  constexpr int TI = (MT == 128) ? 4 : 2;
  constexpr int TJ = (MT == 128) ? 3 : 2;
  __shared__ u16 As[2][MT * 32];
  __shared__ u16 Bs[2][NT * 32];
  const int tid = threadIdx.x;
  const int lane = tid & 63;
  const int wid = tid >> 6;
  const int qd = lane >> 4;
  const int m16 = lane & 15;
  const int rowbase = (MT == 128) ? (wid >> 1) * 64 : 0;
  const int colbase = (MT == 128) ? (wid & 1) * 48 : wid * 32;
  const int m0 = blockIdx.x * MT, n0 = blockIdx.y * NT;

  f32x4 acc[TI][TJ];
#pragma unroll
  for (int i = 0; i < TI; ++i)
#pragma unroll
    for (int j = 0; j < TJ; ++j)
#pragma unroll
      for (int e = 0; e < 4; ++e) acc[i][j][e] = 0.f;

  // stage one 32-wide K-slice of A and B into buffer `buf`
  auto stage = [&](int buf, int k0) {
#pragma unroll
    for (int p = tid; p < MT * 4; p += 256) {
      int row = p >> 2;
      int g = (p & 3) ^ ((row >> 1) & 3);
      gld16(A + (size_t)(m0 + row) * K + k0 + g * 8, &As[buf][(p - lane) * 8]);
    }
#pragma unroll
    for (int p = tid; p < NT * 4; p += 256) {
      int row = p >> 2;
      int g = (p & 3) ^ ((row >> 1) & 3);
      gld16(B + (size_t)(n0 + row) * K + k0 + g * 8, &Bs[buf][(p - lane) * 8]);
    }
  };

  stage(0, 0);                       // prologue
  int cur = 0;
  for (int k0 = 0; k0 < K; k0 += 32) {
    __syncthreads();                 // buf[cur] staged (issued last iter); prev reads done
    if (k0 + 32 < K) stage(cur ^ 1, k0 + 32);
    const u16* as = As[cur];
    const u16* bs = Bs[cur];
    short8 af[TI], bf[TJ];
#pragma unroll
    for (int i = 0; i < TI; ++i) {
      int ar = rowbase + i * 16 + m16;
      af[i] = *(const short8*)&as[(ar * 4 + (qd ^ ((ar >> 1) & 3))) * 8];
    }
#pragma unroll
    for (int j = 0; j < TJ; ++j) {
      int br = colbase + j * 16 + m16;
      bf[j] = *(const short8*)&bs[(br * 4 + (qd ^ ((br >> 1) & 3))) * 8];
    }
#pragma unroll
    for (int i = 0; i < TI; ++i)
#pragma unroll
      for (int j = 0; j < TJ; ++j)
        acc[i][j] = __builtin_amdgcn_mfma_f32_16x16x32_bf16(af[i], bf[j], acc[i][j], 0, 0, 0);
    cur ^= 1;
  }

  // C/D layout: col = m16, row = qd*4 + reg
#pragma unroll
  for (int i = 0; i < TI; ++i) {
    int gr = m0 + rowbase + i * 16 + qd * 4;
#pragma unroll
    for (int j = 0; j < TJ; ++j) {
      int gc = n0 + colbase + j * 16 + m16;
      if (mode == 0) {
        if (gc < 768) {
          float bias = bq[gc];
          int h = gc >> 6, d = gc & 63;
          // fold attention scale 1/8 and log2(e) into Q: exp(x/8) = exp2(x*0.18034)
#pragma unroll
          for (int r = 0; r < 4; ++r)
            qo[((size_t)h * 4096 + gr + r) * 64 + d] = f2bf((acc[i][j][r] + bias) * 0.18033688f);
        } else if (gc < 1536) {
          int c = gc - 768;
          float bias = bk[c];
          int h = c >> 6, d = c & 63;
#pragma unroll
          for (int r = 0; r < 4; ++r)
            ko[((size_t)h * 4096 + gr + r) * 64 + d] = f2bf(acc[i][j][r] + bias);
        } else {
          int c = gc - 1536;
          float bias = bv[c];
          int h = c >> 6, d = c & 63;
          u16x4 pk;
#pragma unroll
          for (int r = 0; r < 4; ++r) pk[r] = f2bf(acc[i][j][r] + bias);
          *(u16x4*)&vto[((size_t)h * 64 + d) * 4096 + gr] = pk;
        }
      } else {
        float bias = bo[gc];
#pragma unroll
        for (int r = 0; r < 4; ++r)
          fo[(size_t)(gr + r) * 768 + gc] = acc[i][j][r] + bias;
      }
    }
  }
}

// ---------------- flash attention fwd (S^T form, fixed-max base-2 softmax) ----------------
// grid (12*kspl groups=(h,z), 16 qblocks), 512 thr / 8 WAVES. Wave owns ONE 32-q-row tile.
// (r12 best-measured: 66.1us, MfmaUtil ~32%, VGPR 60 — LOCKED. r15's dual-pipe reorder was
//  mildly negative: compiler already interleaves softmax VALU with in-flight MFMAs in the
//  barrier-free region; explicit batching only raised VGPR 60->64 and stretched s0's live
//  range. Remaining ~25us over the ~40us pipe floor is barrier drain — only reachable via
//  counted-vmcnt/raw-barrier structure that failed the harness twice, r3/r4.)
// 8 waves amortize each staged 16KB K/V tile over 256 q-rows; 768 blocks = 3/CU; XCD
// clustering (48%8==0 -> id%8 = grp%8) keeps K/V streams L2-resident (r5: FETCH /4.5).
// V LDS staging is the layout transform (r7: global-direct V = 2x regression, uncoalesced).
// Sync = PROVEN syncthreads double-buffer.
// O-partials stored as BF16 (r12: halves attn WRITE + merge read; error <=8e-5). l stays f32.
// 32x32x16 MFMA. Swapped QK^T: S^T = K*Q^T, lane (q32=lane&31, hf=lane>>5) holds 16 scores
// of q-row q32, k = (reg&3)+8*(reg>>2)+4*hf. Softmax in-register; P for PV built via
// v_cvt_pk_bf16_f32 + permlane32_swap pairing (w0,w2)/(w1,w3) -> A-frag layout k=(l>>5)*8+j.
// K buf 64x64 (8 chunks/row, phys = row*8 + (c ^ (row&7))); V^T buf 64d x 64k same swizzle,
// double-buffered, 32 KB LDS.
__global__ __launch_bounds__(512, 4) void attn_fwd(
    const u16* __restrict__ Q, const u16* __restrict__ Kg, const u16* __restrict__ Vt,
    u16* __restrict__ Opart, float* __restrict__ lpart, u16* __restrict__ abo, int kspl) {
  __shared__ u16 Ks[2][64 * 64];
  __shared__ u16 Vs[2][64 * 64];
  const int tid = threadIdx.x, lane = tid & 63, wid = tid >> 6;
  const int q32 = lane & 31, hf = lane >> 5;
  const int grp = blockIdx.x;
  const int h = grp / kspl;
  const int z = grp - h * kspl;
  const int qrow = blockIdx.y * 256 + wid * 32;
  const int kbase = z * (4096 / kspl);
  const int niter = (4096 / kspl) >> 6;

  const u16* kgh = Kg + (size_t)h * 4096 * 64;
  const u16* vth = Vt + (size_t)h * 64 * 4096;

  // Q fragment (B-operand of K*Q^T): qf[ds] = Q[qrow+q32][ds*16 + hf*8 ..+8)
  short8 qf[4];
  {
    const u16* qb = Q + ((size_t)h * 4096 + qrow + q32) * 64 + hf * 8;
#pragma unroll
    for (int ds = 0; ds < 4; ++ds) qf[ds] = *(const short8*)(qb + ds * 16);
  }

  float lrun = 0.f;
  f32x16 oacc[2];
#pragma unroll
  for (int d = 0; d < 2; ++d)
#pragma unroll
    for (int r = 0; r < 16; ++r) oacc[d][r] = 0.f;

  // persistent zero C-operand for the QK MFMA chain (avoids re-zeroing 16 regs per subtile)
  f32x16 zv;
#pragma unroll
  for (int r = 0; r < 16; ++r) zv[r] = 0.f;

  // prologue: stage iter 0 into buffer 0 (512 thr -> 1 K-chunk + 1 V-chunk each)
  {
    const int kt = kbase;
    int p = tid;                              // 0..511 chunks
    int row = p >> 3;
    int g = (p & 7) ^ (row & 7);
    gld16(kgh + (size_t)(kt + row) * 64 + g * 8, &Ks[0][(p - lane) * 8]);
    gld16(vth + (size_t)row * 4096 + kt + g * 8, &Vs[0][(p - lane) * 8]);
  }

  for (int it = 0; it < niter; ++it) {
    __syncthreads();   // buf[it&1] staged (issued last iter); prev reads of buf^1 done
    if (it + 1 < niter) {
      const int kt = kbase + (it + 1) * 64;
      const int b = (it + 1) & 1;
      int p = tid;
      int row = p >> 3;
      int g = (p & 7) ^ (row & 7);
      gld16(kgh + (size_t)(kt + row) * 64 + g * 8, &Ks[b][(p - lane) * 8]);
      gld16(vth + (size_t)row * 4096 + kt + g * 8, &Vs[b][(p - lane) * 8]);
    }
    const u16* ks = Ks[it & 1];
    const u16* vs = Vs[it & 1];

#pragma unroll
    for (int kst = 0; kst < 2; ++kst) {       // 32-k subtile
      const int krow = kst * 32 + q32;
      short8 kf[4];
#pragma unroll
      for (int ds = 0; ds < 4; ++ds) {
        int c = ds * 2 + hf;
        kf[ds] = *(const short8*)&ks[((krow << 3) + (c ^ (krow & 7))) * 8];
      }
      f32x16 s;
      __builtin_amdgcn_s_setprio(1);
      s = __builtin_amdgcn_mfma_f32_32x32x16_bf16(kf[0], qf[0], zv, 0, 0, 0);
#pragma unroll
      for (int ds = 1; ds < 4; ++ds)
        s = __builtin_amdgcn_mfma_f32_32x32x16_bf16(kf[ds], qf[ds], s, 0, 0, 0);
      __builtin_amdgcn_s_setprio(0);
      unsigned w[8];
      float ls0 = 0.f, ls1 = 0.f;
#pragma unroll
      for (int i = 0; i < 8; ++i) {
        float p0 = __builtin_amdgcn_exp2f(s[2 * i]);
        float p1 = __builtin_amdgcn_exp2f(s[2 * i + 1]);
        if (i & 1) ls1 += p0 + p1; else ls0 += p0 + p1;
        asm("v_cvt_pk_bf16_f32 %0, %1, %2" : "=v"(w[i]) : "v"(p0), "v"(p1));
      }
      lrun += ls0 + ls1;
      uint2v r0 = __builtin_amdgcn_permlane32_swap(w[0], w[2], false, false);
      uint2v r1 = __builtin_amdgcn_permlane32_swap(w[1], w[3], false, false);
      uint2v r2 = __builtin_amdgcn_permlane32_swap(w[4], w[6], false, false);
      uint2v r3 = __builtin_amdgcn_permlane32_swap(w[5], w[7], false, false);
      short8 pa[2];
      pa[0] = mk8(r0[0], r1[0], r0[1], r1[1]);   // k-slice kst*32 + [0,16)
      pa[1] = mk8(r2[0], r3[0], r2[1], r3[1]);   // k-slice kst*32 + [16,32)
      // O += P V for this subtile (all in registers; V from swizzled LDS)
      __builtin_amdgcn_s_setprio(1);
#pragma unroll
      for (int dt = 0; dt < 2; ++dt) {
        const int vrow = dt * 32 + q32;
#pragma unroll
        for (int ksl = 0; ksl < 2; ++ksl) {
          int c = kst * 4 + ksl * 2 + hf;
          short8 vf = *(const short8*)&vs[((vrow << 3) + (c ^ (vrow & 7))) * 8];
          oacc[dt] = __builtin_amdgcn_mfma_f32_32x32x16_bf16(pa[ksl], vf, oacc[dt], 0, 0, 0);
        }
      }
      __builtin_amdgcn_s_setprio(0);
    }
  }

  // each half holds a disjoint k-partial of the row sum; combine across halves
  lrun += __shfl_xor(lrun, 32);

  if (kspl > 1) {
    if (hf == 0)
      lpart[((size_t)z * 4096 + qrow + q32) * 12 + h] = lrun;
    u16* ob = Opart + (size_t)z * 4096 * 768;
#pragma unroll
    for (int r = 0; r < 16; ++r) {
      int qloc = (r & 3) + 8 * (r >> 2) + 4 * hf;
#pragma unroll
      for (int dt = 0; dt < 2; ++dt)
        ob[(size_t)(qrow + qloc) * 768 + h * 64 + dt * 32 + q32] = f2bf(oacc[dt][r]);
    }
  } else {
    float linv = 1.0f / lrun;
#pragma unroll
    for (int r = 0; r < 16; ++r) {
      int qloc = (r & 3) + 8 * (r >> 2) + 4 * hf;
      float li = __shfl(linv, qloc);
#pragma unroll
      for (int dt = 0; dt < 2; ++dt)
        abo[(size_t)(qrow + qloc) * 768 + h * 64 + dt * 32 + q32] =
            f2bf(oacc[dt][r] * li);
    }
  }
}

// ---------------- merge ksp k-split bf16 partials + normalize -> bf16, x8 ----------------
// ROUND-16: widened 4->8 bf16/thread (16B loads/stores, grid 1536) — per-element arithmetic
// order unchanged -> bit-identical output; halves instruction/address overhead.
__global__ void merge_norm(const u16* __restrict__ Opart, const float* __restrict__ lpart,
                           u16* __restrict__ abo, int ksp) {
  int i = blockIdx.x * 256 + threadIdx.x;   // < 393216 (4096*768/8)
  int s = i / 96, cq = i - s * 96;
  int h = cq >> 3;                          // (cq*8)>>6
  float a[8];
#pragma unroll
  for (int r = 0; r < 8; ++r) a[r] = 0.f;
  float l = 0.f;
  for (int z = 0; z < ksp; ++z) {
    u16x8 b = *(const u16x8*)(Opart + (size_t)z * 4096 * 768 + (size_t)i * 8);
#pragma unroll
    for (int r = 0; r < 8; ++r) a[r] += __uint_as_float((unsigned)b[r] << 16);
    l += lpart[((size_t)z * 4096 + s) * 12 + h];
  }
  float rl = 1.0f / l;
  u16x8 o;
#pragma unroll
  for (int r = 0; r < 8; ++r) o[r] = f2bf(a[r] * rl);
  *(u16x8*)(abo + (size_t)i * 8) = o;
}

extern "C" void kernel_launch(void* const* d_in, const int* in_sizes, int n_in,
                              void* d_out, int out_size, void* d_ws, size_t ws_size,
                              hipStream_t stream) {
  const float* x   = (const float*)d_in[0];
  const float* wq  = (const float*)d_in[1];
  const float* bq  = (const float*)d_in[2];
  const float* wk  = (const float*)d_in[3];
  const float* bk  = (const float*)d_in[4];
  const float* wv  = (const float*)d_in[5];
  const float* bv  = (const float*)d_in[6];
  const float* wo  = (const float*)d_in[7];
  const float* bo  = (const float*)d_in[8];
  const float* dq  = (const float*)d_in[9];
  const float* uq  = (const float*)d_in[10];
  const float* dk  = (const float*)d_in[11];
  const float* uk  = (const float*)d_in[12];
  const float* dv  = (const float*)d_in[13];
  const float* uv  = (const float*)d_in[14];
  float* out = (float*)d_out;

  char* ws = (char*)d_ws;
  u16* xb    = (u16*)(ws);                 // 4096*768 bf16 (6291456 B); dead after QKV gemm
  u16* ab    = (u16*)(ws);                 // aliases xb: attn output [4096][768] bf16
  u16* weff  = (u16*)(ws + 6291456);       // 2304*768
  u16* wob   = (u16*)(ws + 9830400);       // 768*768
  u16* qb    = (u16*)(ws + 11010048);      // [12][4096][64]
  u16* kb    = (u16*)(ws + 17301504);      // [12][4096][64]
  u16* vtb   = (u16*)(ws + 23592960);      // [12][64][4096]
  u16* Op    = (u16*)(ws + 29884416);      // [kspl][4096][768] bf16 (<= 25165824 B)
  float* lp  = (float*)(ws + 55050240);    // [kspl][4096][12]  f32 (<= 786432 B) -> end 55836672

  int kspl = 1;
  if (ws_size >= 55836672ull) kspl = 4;    // bf16 partials: kspl=4 fits in ~56MB
  else if (ws_size >= 42860544ull) kspl = 2;

  prep_all<<<5376, 256, 0, stream>>>(x, xb, wq, wk, wv, dq, uq, dk, uk, dv, uv, wo, weff, wob);
  gemm_nt<128><<<dim3(32, 24), 256, 0, stream>>>(xb, weff, 768, 0, bq, bk, bv, qb, kb, vtb,
                                                 nullptr, nullptr);
  attn_fwd<<<dim3(12 * kspl, 16), 512, 0, stream>>>(qb, kb, vtb, Op, lp, ab, kspl);
  if (kspl > 1) merge_norm<<<1536, 256, 0, stream>>>(Op, lp, ab, kspl);
  gemm_nt<32><<<dim3(128, 6), 256, 0, stream>>>(ab, wob, 768, 1, nullptr, nullptr, nullptr,
                                                nullptr, nullptr, nullptr, bo, out);
}

// Round 18
// 200.736 us; speedup vs baseline: 1.0467x; 1.0059x over previous
//
#include <hip/hip_runtime.h>

typedef unsigned short u16;
typedef __attribute__((ext_vector_type(8))) short short8;    // 8 bf16 (4 VGPRs)
typedef __attribute__((ext_vector_type(4))) float f32x4;
typedef __attribute__((ext_vector_type(16))) float f32x16;
typedef __attribute__((ext_vector_type(4))) unsigned short u16x4;
typedef __attribute__((ext_vector_type(8))) unsigned short u16x8;
typedef __attribute__((ext_vector_type(2))) unsigned int uint2v;

typedef __attribute__((address_space(1))) void as1_void;
typedef __attribute__((address_space(3))) void as3_void;

// async global->LDS, 16B per lane; LDS dest = wave-uniform base + lane*16
__device__ __forceinline__ void gld16(const u16* g, u16* l) {
  __builtin_amdgcn_global_load_lds((as1_void*)g, (as3_void*)l, 16, 0, 0);
}

__device__ __forceinline__ u16 f2bf(float f) {
  unsigned u = __float_as_uint(f);
  u += 0x7fffu + ((u >> 16) & 1u);   // RNE
  return (u16)(u >> 16);
}

__device__ __forceinline__ short8 mk8(unsigned a, unsigned b, unsigned c, unsigned d) {
  union { unsigned u[4]; short8 s; } x;
  x.u[0] = a; x.u[1] = b; x.u[2] = c; x.u[3] = d;
  return x.s;
}

// ---------------- fused prep: cvt x (x4) + W_eff (x4) + cvt wo (x4) ----------------
// (r17's 8-wide rewrite FAILED verification (absmax 3.2e-2, undiagnosed) — reverted to
//  this r16-proven 4-wide version. blocks [0,3072): x cvt; [3072,4800): weff quads;
//  [4800,5376): wob quads. All x4 vectorized.)
__global__ void prep_all(const float* __restrict__ x, u16* __restrict__ xb,
                         const float* __restrict__ wq, const float* __restrict__ wk, const float* __restrict__ wv,
                         const float* __restrict__ dq, const float* __restrict__ uq,
                         const float* __restrict__ dk, const float* __restrict__ uk,
                         const float* __restrict__ dv, const float* __restrict__ uv,
                         const float* __restrict__ wo, u16* __restrict__ weff, u16* __restrict__ wob) {
  int bid = blockIdx.x;
  if (bid < 3072) {
    int i = bid * 256 + threadIdx.x;          // < 786432
    f32x4 f = *(const f32x4*)(x + (size_t)i * 4);
    u16x4 o;
#pragma unroll
    for (int r = 0; r < 4; ++r) o[r] = f2bf(f[r]);
    *(u16x4*)(xb + (size_t)i * 4) = o;
    return;
  }
  if (bid < 4800) {
    int idx = (bid - 3072) * 256 + threadIdx.x;   // < 442368 quads (2304 rows x 192)
    int n = idx / 192, d4 = (idx - n * 192) * 4;
    const float *w, *dn, *up; int e;
    if (n < 768)       { w = wq; dn = dq; up = uq; e = n; }
    else if (n < 1536) { w = wk; dn = dk; up = uk; e = n - 768; }
    else               { w = wv; dn = dv; up = uv; e = n - 1536; }
    f32x4 acc = *(const f32x4*)(w + (size_t)e * 768 + d4);
    f32x4 lo = {0.f, 0.f, 0.f, 0.f};
#pragma unroll
    for (int r = 0; r < 8; ++r) {
      float u = up[e * 8 + r];
      f32x4 dv4 = *(const f32x4*)(dn + r * 768 + d4);
#pragma unroll
      for (int j = 0; j < 4; ++j) lo[j] += u * dv4[j];
    }
    u16x4 o;
#pragma unroll
    for (int j = 0; j < 4; ++j) o[j] = f2bf(acc[j] + 2.0f * lo[j]);  // SCALING = 2
    *(u16x4*)(weff + (size_t)n * 768 + d4) = o;
    return;
  }
  int idx = (bid - 4800) * 256 + threadIdx.x;     // < 147456 quads (768 x 192)
  f32x4 f = *(const f32x4*)(wo + (size_t)idx * 4);
  u16x4 o;
#pragma unroll
  for (int r = 0; r < 4; ++r) o[r] = f2bf(f[r]);
  *(u16x4*)(wob + (size_t)idx * 4) = o;
}

// ---------------- NT GEMM: C[m,n] = sum_k A[m,k]*B[n,k] (+bias) ----------------
// (r12 best-measured config — LOCKED.)
// MT=128: 128x96 tile, grid (32,24)=768 = exactly 3 blk/CU. 2x2 waves of 64x48 (TI4,TJ3).
// MT=32: 32x128, 1x4 waves of 32x32 (grid (128,6)=768).
// BK=32, 256 thr, double-buffered staging (one barrier per K-step).
// (r11 lesson: no merge fusion here — A-panels reused by col-blocks.)
// mode 0: N=2304 -> q[h][s][64] (pre-scaled by 0.125*log2e), k[h][s][64], vt[h][64][s]
// mode 1: N=768  -> fo[s][768] fp32 (+bo)
template <int MT>
__global__ __launch_bounds__(256) void gemm_nt(
    const u16* __restrict__ A, const u16* __restrict__ B, int K, int mode,
    const float* __restrict__ bq, const float* __restrict__ bk, const float* __restrict__ bv,
    u16* __restrict__ qo, u16* __restrict__ ko, u16* __restrict__ vto,
    const float* __restrict__ bo, float* __restrict__ fo) {
  constexpr int NT = (MT == 128) ? 96 : 128;
  constexpr int TI = (MT == 128) ? 4 : 2;
  constexpr int TJ = (MT == 128) ? 3 : 2;
  __shared__ u16 As[2][MT * 32];
  __shared__ u16 Bs[2][NT * 32];
  const int tid = threadIdx.x;
  const int lane = tid & 63;
  const int wid = tid >> 6;
  const int qd = lane >> 4;
  const int m16 = lane & 15;
  const int rowbase = (MT == 128) ? (wid >> 1) * 64 : 0;
  const int colbase = (MT == 128) ? (wid & 1) * 48 : wid * 32;
  const int m0 = blockIdx.x * MT, n0 = blockIdx.y * NT;

  f32x4 acc[TI][TJ];
#pragma unroll
  for (int i = 0; i < TI; ++i)
#pragma unroll
    for (int j = 0; j < TJ; ++j)
#pragma unroll
      for (int e = 0; e < 4; ++e) acc[i][j][e] = 0.f;

  // stage one 32-wide K-slice of A and B into buffer `buf`
  auto stage = [&](int buf, int k0) {
#pragma unroll
    for (int p = tid; p < MT * 4; p += 256) {
      int row = p >> 2;
      int g = (p & 3) ^ ((row >> 1) & 3);
      gld16(A + (size_t)(m0 + row) * K + k0 + g * 8, &As[buf][(p - lane) * 8]);
    }
#pragma unroll
    for (int p = tid; p < NT * 4; p += 256) {
      int row = p >> 2;
      int g = (p & 3) ^ ((row >> 1) & 3);
      gld16(B + (size_t)(n0 + row) * K + k0 + g * 8, &Bs[buf][(p - lane) * 8]);
    }
  };

  stage(0, 0);                       // prologue
  int cur = 0;
  for (int k0 = 0; k0 < K; k0 += 32) {
    __syncthreads();                 // buf[cur] staged (issued last iter); prev reads done
    if (k0 + 32 < K) stage(cur ^ 1, k0 + 32);
    const u16* as = As[cur];
    const u16* bs = Bs[cur];
    short8 af[TI], bf[TJ];
#pragma unroll
    for (int i = 0; i < TI; ++i) {
      int ar = rowbase + i * 16 + m16;
      af[i] = *(const short8*)&as[(ar * 4 + (qd ^ ((ar >> 1) & 3))) * 8];
    }
#pragma unroll
    for (int j = 0; j < TJ; ++j) {
      int br = colbase + j * 16 + m16;
      bf[j] = *(const short8*)&bs[(br * 4 + (qd ^ ((br >> 1) & 3))) * 8];
    }
#pragma unroll
    for (int i = 0; i < TI; ++i)
#pragma unroll
      for (int j = 0; j < TJ; ++j)
        acc[i][j] = __builtin_amdgcn_mfma_f32_16x16x32_bf16(af[i], bf[j], acc[i][j], 0, 0, 0);
    cur ^= 1;
  }

  // C/D layout: col = m16, row = qd*4 + reg
#pragma unroll
  for (int i = 0; i < TI; ++i) {
    int gr = m0 + rowbase + i * 16 + qd * 4;
#pragma unroll
    for (int j = 0; j < TJ; ++j) {
      int gc = n0 + colbase + j * 16 + m16;
      if (mode == 0) {
        if (gc < 768) {
          float bias = bq[gc];
          int h = gc >> 6, d = gc & 63;
          // fold attention scale 1/8 and log2(e) into Q: exp(x/8) = exp2(x*0.18034)
#pragma unroll
          for (int r = 0; r < 4; ++r)
            qo[((size_t)h * 4096 + gr + r) * 64 + d] = f2bf((acc[i][j][r] + bias) * 0.18033688f);
        } else if (gc < 1536) {
          int c = gc - 768;
          float bias = bk[c];
          int h = c >> 6, d = c & 63;
#pragma unroll
          for (int r = 0; r < 4; ++r)
            ko[((size_t)h * 4096 + gr + r) * 64 + d] = f2bf(acc[i][j][r] + bias);
        } else {
          int c = gc - 1536;
          float bias = bv[c];
          int h = c >> 6, d = c & 63;
          u16x4 pk;
#pragma unroll
          for (int r = 0; r < 4; ++r) pk[r] = f2bf(acc[i][j][r] + bias);
          *(u16x4*)&vto[((size_t)h * 64 + d) * 4096 + gr] = pk;
        }
      } else {
        float bias = bo[gc];
#pragma unroll
        for (int r = 0; r < 4; ++r)
          fo[(size_t)(gr + r) * 768 + gc] = acc[i][j][r] + bias;
      }
    }
  }
}

// ---------------- flash attention fwd (S^T form, fixed-max base-2 softmax) ----------------
// grid (12*kspl groups=(h,z), 16 qblocks), 512 thr / 8 WAVES. Wave owns ONE 32-q-row tile.
// (r12 best-measured: ~66.2us, MfmaUtil ~32%, VGPR 60 — LOCKED. Per-iter wall ~9.9k cyc >>
//  L2 latency, so barrier finds vmcnt ~0 — no drain cost; kernel is mid-occupancy
//  latency-limited with no saturated pipe. Safe levers exhausted: waves r2/r8 captured,
//  traffic r12 captured, reorder r15 refuted, counted-vmcnt r3/r4 harness-lethal.)
// 8 waves amortize each staged 16KB K/V tile over 256 q-rows; 768 blocks = 3/CU; XCD
// clustering (48%8==0 -> id%8 = grp%8) keeps K/V streams L2-resident (r5: FETCH /4.5).
// V LDS staging is the layout transform (r7: global-direct V = 2x regression, uncoalesced).
// Sync = PROVEN syncthreads double-buffer.
// O-partials stored as BF16 (r12: halves attn WRITE + merge read; error <=8e-5). l stays f32.
// 32x32x16 MFMA. Swapped QK^T: S^T = K*Q^T, lane (q32=lane&31, hf=lane>>5) holds 16 scores
// of q-row q32, k = (reg&3)+8*(reg>>2)+4*hf. Softmax in-register; P for PV built via
// v_cvt_pk_bf16_f32 + permlane32_swap pairing (w0,w2)/(w1,w3) -> A-frag layout k=(l>>5)*8+j.
// K buf 64x64 (8 chunks/row, phys = row*8 + (c ^ (row&7))); V^T buf 64d x 64k same swizzle,
// double-buffered, 32 KB LDS.
__global__ __launch_bounds__(512, 4) void attn_fwd(
    const u16* __restrict__ Q, const u16* __restrict__ Kg, const u16* __restrict__ Vt,
    u16* __restrict__ Opart, float* __restrict__ lpart, u16* __restrict__ abo, int kspl) {
  __shared__ u16 Ks[2][64 * 64];
  __shared__ u16 Vs[2][64 * 64];
  const int tid = threadIdx.x, lane = tid & 63, wid = tid >> 6;
  const int q32 = lane & 31, hf = lane >> 5;
  const int grp = blockIdx.x;
  const int h = grp / kspl;
  const int z = grp - h * kspl;
  const int qrow = blockIdx.y * 256 + wid * 32;
  const int kbase = z * (4096 / kspl);
  const int niter = (4096 / kspl) >> 6;

  const u16* kgh = Kg + (size_t)h * 4096 * 64;
  const u16* vth = Vt + (size_t)h * 64 * 4096;

  // Q fragment (B-operand of K*Q^T): qf[ds] = Q[qrow+q32][ds*16 + hf*8 ..+8)
  short8 qf[4];
  {
    const u16* qb = Q + ((size_t)h * 4096 + qrow + q32) * 64 + hf * 8;
#pragma unroll
    for (int ds = 0; ds < 4; ++ds) qf[ds] = *(const short8*)(qb + ds * 16);
  }

  float lrun = 0.f;
  f32x16 oacc[2];
#pragma unroll
  for (int d = 0; d < 2; ++d)
#pragma unroll
    for (int r = 0; r < 16; ++r) oacc[d][r] = 0.f;

  // persistent zero C-operand for the QK MFMA chain (avoids re-zeroing 16 regs per subtile)
  f32x16 zv;
#pragma unroll
  for (int r = 0; r < 16; ++r) zv[r] = 0.f;

  // prologue: stage iter 0 into buffer 0 (512 thr -> 1 K-chunk + 1 V-chunk each)
  {
    const int kt = kbase;
    int p = tid;                              // 0..511 chunks
    int row = p >> 3;
    int g = (p & 7) ^ (row & 7);
    gld16(kgh + (size_t)(kt + row) * 64 + g * 8, &Ks[0][(p - lane) * 8]);
    gld16(vth + (size_t)row * 4096 + kt + g * 8, &Vs[0][(p - lane) * 8]);
  }

  for (int it = 0; it < niter; ++it) {
    __syncthreads();   // buf[it&1] staged (issued last iter); prev reads of buf^1 done
    if (it + 1 < niter) {
      const int kt = kbase + (it + 1) * 64;
      const int b = (it + 1) & 1;
      int p = tid;
      int row = p >> 3;
      int g = (p & 7) ^ (row & 7);
      gld16(kgh + (size_t)(kt + row) * 64 + g * 8, &Ks[b][(p - lane) * 8]);
      gld16(vth + (size_t)row * 4096 + kt + g * 8, &Vs[b][(p - lane) * 8]);
    }
    const u16* ks = Ks[it & 1];
    const u16* vs = Vs[it & 1];

#pragma unroll
    for (int kst = 0; kst < 2; ++kst) {       // 32-k subtile
      const int krow = kst * 32 + q32;
      short8 kf[4];
#pragma unroll
      for (int ds = 0; ds < 4; ++ds) {
        int c = ds * 2 + hf;
        kf[ds] = *(const short8*)&ks[((krow << 3) + (c ^ (krow & 7))) * 8];
      }
      f32x16 s;
      __builtin_amdgcn_s_setprio(1);
      s = __builtin_amdgcn_mfma_f32_32x32x16_bf16(kf[0], qf[0], zv, 0, 0, 0);
#pragma unroll
      for (int ds = 1; ds < 4; ++ds)
        s = __builtin_amdgcn_mfma_f32_32x32x16_bf16(kf[ds], qf[ds], s, 0, 0, 0);
      __builtin_amdgcn_s_setprio(0);
      unsigned w[8];
      float ls0 = 0.f, ls1 = 0.f;
#pragma unroll
      for (int i = 0; i < 8; ++i) {
        float p0 = __builtin_amdgcn_exp2f(s[2 * i]);
        float p1 = __builtin_amdgcn_exp2f(s[2 * i + 1]);
        if (i & 1) ls1 += p0 + p1; else ls0 += p0 + p1;
        asm("v_cvt_pk_bf16_f32 %0, %1, %2" : "=v"(w[i]) : "v"(p0), "v"(p1));
      }
      lrun += ls0 + ls1;
      uint2v r0 = __builtin_amdgcn_permlane32_swap(w[0], w[2], false, false);
      uint2v r1 = __builtin_amdgcn_permlane32_swap(w[1], w[3], false, false);
      uint2v r2 = __builtin_amdgcn_permlane32_swap(w[4], w[6], false, false);
      uint2v r3 = __builtin_amdgcn_permlane32_swap(w[5], w[7], false, false);
      short8 pa[2];
      pa[0] = mk8(r0[0], r1[0], r0[1], r1[1]);   // k-slice kst*32 + [0,16)
      pa[1] = mk8(r2[0], r3[0], r2[1], r3[1]);   // k-slice kst*32 + [16,32)
      // O += P V for this subtile (all in registers; V from swizzled LDS)
      __builtin_amdgcn_s_setprio(1);
#pragma unroll
      for (int dt = 0; dt < 2; ++dt) {
        const int vrow = dt * 32 + q32;
#pragma unroll
        for (int ksl = 0; ksl < 2; ++ksl) {
          int c = kst * 4 + ksl * 2 + hf;
          short8 vf = *(const short8*)&vs[((vrow << 3) + (c ^ (vrow & 7))) * 8];
          oacc[dt] = __builtin_amdgcn_mfma_f32_32x32x16_bf16(pa[ksl], vf, oacc[dt], 0, 0, 0);
        }
      }
      __builtin_amdgcn_s_setprio(0);
    }
  }

  // each half holds a disjoint k-partial of the row sum; combine across halves
  lrun += __shfl_xor(lrun, 32);

  if (kspl > 1) {
    if (hf == 0)
      lpart[((size_t)z * 4096 + qrow + q32) * 12 + h] = lrun;
    u16* ob = Opart + (size_t)z * 4096 * 768;
#pragma unroll
    for (int r = 0; r < 16; ++r) {
      int qloc = (r & 3) + 8 * (r >> 2) + 4 * hf;
#pragma unroll
      for (int dt = 0; dt < 2; ++dt)
        ob[(size_t)(qrow + qloc) * 768 + h * 64 + dt * 32 + q32] = f2bf(oacc[dt][r]);
    }
  } else {
    float linv = 1.0f / lrun;
#pragma unroll
    for (int r = 0; r < 16; ++r) {
      int qloc = (r & 3) + 8 * (r >> 2) + 4 * hf;
      float li = __shfl(linv, qloc);
#pragma unroll
      for (int dt = 0; dt < 2; ++dt)
        abo[(size_t)(qrow + qloc) * 768 + h * 64 + dt * 32 + q32] =
            f2bf(oacc[dt][r] * li);
    }
  }
}

// ---------------- merge ksp k-split bf16 partials + normalize -> bf16, x8 ----------------
// (r16: widened to 8 bf16/thread, 16B loads/stores, grid 1536 — verified bit-identical.)
__global__ void merge_norm(const u16* __restrict__ Opart, const float* __restrict__ lpart,
                           u16* __restrict__ abo, int ksp) {
  int i = blockIdx.x * 256 + threadIdx.x;   // < 393216 (4096*768/8)
  int s = i / 96, cq = i - s * 96;
  int h = cq >> 3;                          // (cq*8)>>6
  float a[8];
#pragma unroll
  for (int r = 0; r < 8; ++r) a[r] = 0.f;
  float l = 0.f;
  for (int z = 0; z < ksp; ++z) {
    u16x8 b = *(const u16x8*)(Opart + (size_t)z * 4096 * 768 + (size_t)i * 8);
#pragma unroll
    for (int r = 0; r < 8; ++r) a[r] += __uint_as_float((unsigned)b[r] << 16);
    l += lpart[((size_t)z * 4096 + s) * 12 + h];
  }
  float rl = 1.0f / l;
  u16x8 o;
#pragma unroll
  for (int r = 0; r < 8; ++r) o[r] = f2bf(a[r] * rl);
  *(u16x8*)(abo + (size_t)i * 8) = o;
}

extern "C" void kernel_launch(void* const* d_in, const int* in_sizes, int n_in,
                              void* d_out, int out_size, void* d_ws, size_t ws_size,
                              hipStream_t stream) {
  const float* x   = (const float*)d_in[0];
  const float* wq  = (const float*)d_in[1];
  const float* bq  = (const float*)d_in[2];
  const float* wk  = (const float*)d_in[3];
  const float* bk  = (const float*)d_in[4];
  const float* wv  = (const float*)d_in[5];
  const float* bv  = (const float*)d_in[6];
  const float* wo  = (const float*)d_in[7];
  const float* bo  = (const float*)d_in[8];
  const float* dq  = (const float*)d_in[9];
  const float* uq  = (const float*)d_in[10];
  const float* dk  = (const float*)d_in[11];
  const float* uk  = (const float*)d_in[12];
  const float* dv  = (const float*)d_in[13];
  const float* uv  = (const float*)d_in[14];
  float* out = (float*)d_out;

  char* ws = (char*)d_ws;
  u16* xb    = (u16*)(ws);                 // 4096*768 bf16 (6291456 B); dead after QKV gemm
  u16* ab    = (u16*)(ws);                 // aliases xb: attn output [4096][768] bf16
  u16* weff  = (u16*)(ws + 6291456);       // 2304*768
  u16* wob   = (u16*)(ws + 9830400);       // 768*768
  u16* qb    = (u16*)(ws + 11010048);      // [12][4096][64]
  u16* kb    = (u16*)(ws + 17301504);      // [12][4096][64]
  u16* vtb   = (u16*)(ws + 23592960);      // [12][64][4096]
  u16* Op    = (u16*)(ws + 29884416);      // [kspl][4096][768] bf16 (<= 25165824 B)
  float* lp  = (float*)(ws + 55050240);    // [kspl][4096][12]  f32 (<= 786432 B) -> end 55836672

  int kspl = 1;
  if (ws_size >= 55836672ull) kspl = 4;    // bf16 partials: kspl=4 fits in ~56MB
  else if (ws_size >= 42860544ull) kspl = 2;

  prep_all<<<5376, 256, 0, stream>>>(x, xb, wq, wk, wv, dq, uq, dk, uk, dv, uv, wo, weff, wob);
  gemm_nt<128><<<dim3(32, 24), 256, 0, stream>>>(xb, weff, 768, 0, bq, bk, bv, qb, kb, vtb,
                                                 nullptr, nullptr);
  attn_fwd<<<dim3(12 * kspl, 16), 512, 0, stream>>>(qb, kb, vtb, Op, lp, ab, kspl);
  if (kspl > 1) merge_norm<<<1536, 256, 0, stream>>>(Op, lp, ab, kspl);
  gemm_nt<32><<<dim3(128, 6), 256, 0, stream>>>(ab, wob, 768, 1, nullptr, nullptr, nullptr,
                                                nullptr, nullptr, nullptr, bo, out);
}